// Round 3
// baseline (359.463 us; speedup 1.0000x reference)
//
#include <hip/hip_runtime.h>
#include <hip/hip_bf16.h>

#define NN 100000
#define NE 1280000
#define DD 64
#define NBLK 98              // scan blocks of 1024 nodes
#define NPAD (NBLK * 1024)   // 100352 (padded node count, deg=0 in pad)

typedef __attribute__((ext_vector_type(8))) short bf16x8;
typedef __attribute__((ext_vector_type(4))) float f32x4;

static __device__ __forceinline__ unsigned short f2bf(float f) {
    __hip_bfloat16 h = __float2bfloat16(f);
    return *reinterpret_cast<unsigned short*>(&h);
}

// ---------------------------------------------------------------------------
// x (fp32) -> bf16 copy. Grid 6250 x 256, 4 elems/thread (exact: 6.4M).
// ---------------------------------------------------------------------------
__global__ __launch_bounds__(256) void f32_to_bf16_kernel(
    const float* __restrict__ in, unsigned short* __restrict__ out)
{
    int i = (blockIdx.x * 256 + threadIdx.x) * 4;
    float4 v = *(const float4*)(in + i);
    ushort4 o;
    o.x = f2bf(v.x); o.y = f2bf(v.y); o.z = f2bf(v.z); o.w = f2bf(v.w);
    *(ushort4*)(out + i) = o;
}

// ---------------------------------------------------------------------------
// B-fragment pre-pack: Bp[layer][t][256 threads][8] bf16 so the fused GEMM
// loads its 4 ksteps with 4 dwordx4 loads. Grid 3 (one block per layer).
// ---------------------------------------------------------------------------
__global__ __launch_bounds__(256) void bpack_kernel(
    const float* __restrict__ Wrel1, const float* __restrict__ Wroot1,
    const float* __restrict__ Wrel2, const float* __restrict__ Wroot2,
    const float* __restrict__ Wrel3, const float* __restrict__ Wroot3,
    unsigned short* __restrict__ Bp)
{
    int L = blockIdx.x;
    const float* Wrel  = (L == 0) ? Wrel1  : (L == 1) ? Wrel2  : Wrel3;
    const float* Wroot = (L == 0) ? Wroot1 : (L == 1) ? Wroot2 : Wroot3;
    int tid = threadIdx.x;
    int wv = tid >> 6, lane = tid & 63, quad = lane >> 4, m16 = lane & 15;
    int n = wv * 16 + m16;
    unsigned short* o = Bp + (size_t)L * 4 * 256 * 8;
#pragma unroll
    for (int t = 0; t < 4; ++t)
#pragma unroll
        for (int j = 0; j < 8; ++j) {
            int k = t * 32 + quad * 8 + j;
            float wval = (k < 64) ? Wrel[k * 64 + n] : Wroot[(k - 64) * 64 + n];
            o[((size_t)t * 256 + tid) * 8 + j] = f2bf(wval);
        }
}

// ---------------------------------------------------------------------------
// Degree histogram: 1.28M global atomics over 100K counters (6250 lines).
// No barriers, no return value -> pure throughput at the L2 atomic units.
// ---------------------------------------------------------------------------
__global__ __launch_bounds__(256) void degcnt_kernel(
    const int* __restrict__ dst, int* __restrict__ deg)
{
    int e0 = (blockIdx.x * 256 + threadIdx.x) * 4;
    int4 d4 = *(const int4*)(dst + e0);
    atomicAdd(&deg[d4.x], 1);
    atomicAdd(&deg[d4.y], 1);
    atomicAdd(&deg[d4.z], 1);
    atomicAdd(&deg[d4.w], 1);
}

// ---------------------------------------------------------------------------
// Hierarchical scan of deg[NPAD] -> rowptr/cur. Step 1: block sums (grid 98).
// ---------------------------------------------------------------------------
__global__ __launch_bounds__(256) void bsum_kernel(
    const int* __restrict__ deg, int* __restrict__ bsum)
{
    __shared__ int sd[256];
    int tid = threadIdx.x;
    int4 c = *(const int4*)(deg + blockIdx.x * 1024 + tid * 4);
    sd[tid] = c.x + c.y + c.z + c.w;
    __syncthreads();
    for (int o = 128; o > 0; o >>= 1) {
        if (tid < o) sd[tid] += sd[tid + o];
        __syncthreads();
    }
    if (tid == 0) bsum[blockIdx.x] = sd[0];
}

// Step 2: exclusive scan of 98 block sums (1 block).
__global__ __launch_bounds__(128) void scan98_kernel(
    const int* __restrict__ bsum, int* __restrict__ bbase,
    int* __restrict__ rowptr)
{
    __shared__ int sd[128];
    int tid = threadIdx.x;
    int v = (tid < NBLK) ? bsum[tid] : 0;
    sd[tid] = v;
    __syncthreads();
    for (int o = 1; o < 128; o <<= 1) {
        int t = (tid >= o) ? sd[tid - o] : 0;
        __syncthreads();
        sd[tid] += t;
        __syncthreads();
    }
    if (tid < NBLK) bbase[tid] = sd[tid] - v;
    if (tid == 0) rowptr[NN] = NE;
}

// Step 3: per-block scan of 1024 degs + block base -> rowptr + cur (grid 98).
__global__ __launch_bounds__(256) void bscan_kernel(
    const int* __restrict__ deg, const int* __restrict__ bbase,
    int* __restrict__ rowptr, int* __restrict__ cur)
{
    __shared__ int ssum[256];
    int tid = threadIdx.x;
    int n0 = blockIdx.x * 1024 + tid * 4;
    int4 c = *(const int4*)(deg + n0);
    int s = c.x + c.y + c.z + c.w;
    ssum[tid] = s;
    __syncthreads();
    for (int o = 1; o < 256; o <<= 1) {
        int t = (tid >= o) ? ssum[tid - o] : 0;
        __syncthreads();
        ssum[tid] += t;
        __syncthreads();
    }
    int base = bbase[blockIdx.x] + ssum[tid] - s;
    int4 r;
    r.x = base; r.y = base + c.x; r.z = r.y + c.y; r.w = r.z + c.z;
    *(int4*)(rowptr + n0) = r;
    *(int4*)(cur + n0) = r;
}

// ---------------------------------------------------------------------------
// Direct scatter: pos = atomicAdd(cur[dst]); ebuf[pos] = {src, w}.
// Random 8B writes absorbed by L2/LLC (ebuf is 10.2 MB, LLC-resident).
// ---------------------------------------------------------------------------
__global__ __launch_bounds__(256) void scatter_kernel(
    const int* __restrict__ src, const int* __restrict__ dst,
    const float* __restrict__ w, int* __restrict__ cur,
    int2* __restrict__ ebuf)
{
    int e0 = (blockIdx.x * 256 + threadIdx.x) * 4;
    int4   s4 = *(const int4*)(src + e0);
    int4   d4 = *(const int4*)(dst + e0);
    float4 w4 = *(const float4*)(w + e0);
    int p;
    p = atomicAdd(&cur[d4.x], 1); ebuf[p] = make_int2(s4.x, __float_as_int(w4.x));
    p = atomicAdd(&cur[d4.y], 1); ebuf[p] = make_int2(s4.y, __float_as_int(w4.y));
    p = atomicAdd(&cur[d4.z], 1); ebuf[p] = make_int2(s4.z, __float_as_int(w4.z));
    p = atomicAdd(&cur[d4.w], 1); ebuf[p] = make_int2(s4.w, __float_as_int(w4.w));
}

// ---------------------------------------------------------------------------
// FUSED layer: CSR gather + dual GEMM + bias (+ReLU) in one kernel.
// Block = 512 thr = 8 waves = 16 nodes (one MFMA m-tile). Half-wave per
// node: 32 lanes = 32 channel pairs (u32 = 2 bf16), one full row per
// edge-load, unroll-8 slots -> 16 gathers in flight per wave. Edges staged
// to regs with one cooperative ebuf load, distributed by __shfl. Agg + root
// rows packed into LDS in MFMA fragment order, one barrier, waves 0-3 run
// 4 chained MFMAs + epilogue. Ping-pong in/out tables.
// ---------------------------------------------------------------------------
template <bool RELU, bool OUT32>
__global__ __launch_bounds__(512) void fused_layer_kernel(
    const unsigned short* __restrict__ hb,   // input node table (gather + root)
    const int* __restrict__ rowptr,
    const int2* __restrict__ ebuf,
    const unsigned short* __restrict__ Bp,   // [4][256][8] bf16 (this layer)
    const float* __restrict__ brel,
    void* __restrict__ outp)
{
    __shared__ __align__(16) unsigned int AstW[4 * 256];   // 4 KB

    int tid = threadIdx.x;
    int lane = tid & 63;
    int wv = tid >> 6;            // 0..7
    int half = lane >> 5;         // node parity within wave
    int ch = lane & 31;           // channel pair
    int base = blockIdx.x * 16;
    int node = base + wv * 2 + half;

    const unsigned int* __restrict__ hw = (const unsigned int*)hb;

    // B fragments + bias preloaded (only used by waves 0-3) so their L2
    // latency hides under the gather.
    bf16x8 bfrag[4];
    float bias = 0.f;
    if (wv < 4) {
#pragma unroll
        for (int t2 = 0; t2 < 4; ++t2)
            bfrag[t2] = *(const bf16x8*)(Bp + ((size_t)t2 * 256 + tid) * 8);
        bias = brel[(wv << 4) | (lane & 15)];
    }

    // root row (own node) issued early
    unsigned rootp = hw[(size_t)node * 32 + ch];

    int beg = rowptr[node];
    int end = rowptr[node + 1];
    int deg = end - beg;

    float aL0 = 0.f, aH0 = 0.f, aL1 = 0.f, aH1 = 0.f;
    for (int c = 0; c < deg; c += 32) {
        int rem = deg - c;
        int nsl = rem < 32 ? rem : 32;
        int idx = (ch < nsl) ? (c + ch) : c;
        int2 e = ebuf[beg + idx];
        float wt = (ch < nsl) ? __int_as_float(e.y) : 0.f;

        for (int s0 = 0; s0 < nsl; s0 += 8) {
#pragma unroll
            for (int i = 0; i < 8; ++i) {
                int slot = s0 + i;
                bool ok = slot < nsl;
                int sl = (half << 5) | (ok ? slot : 0);
                int sr = __shfl(e.x, sl);
                float w = __shfl(wt, sl);
                w = ok ? w : 0.f;
                unsigned v = hw[(size_t)sr * 32 + ch];
                if (i & 1) {
                    aL1 = fmaf(w, __uint_as_float(v << 16), aL1);
                    aH1 = fmaf(w, __uint_as_float(v & 0xFFFF0000u), aH1);
                } else {
                    aL0 = fmaf(w, __uint_as_float(v << 16), aL0);
                    aH0 = fmaf(w, __uint_as_float(v & 0xFFFF0000u), aH0);
                }
            }
        }
    }
    float accL = aL0 + aL1, accH = aH0 + aH1;

    // stage agg (k 0..63) and root (k 64..127) pairs in fragment order
    int m = wv * 2 + half;                     // row 0..15
    int t = ch >> 4, q = (ch >> 2) & 3, jj = ch & 3;
    unsigned pack = ((unsigned)f2bf(accH) << 16) | (unsigned)f2bf(accL);
    AstW[t * 256 + (q * 16 + m) * 4 + jj] = pack;
    AstW[(2 + t) * 256 + (q * 16 + m) * 4 + jj] = rootp;
    __syncthreads();

    if (wv < 4) {
        int quad = lane >> 4, m16 = lane & 15;
        int n = wv * 16 + m16;
        f32x4 cacc = {0.f, 0.f, 0.f, 0.f};
#pragma unroll
        for (int t2 = 0; t2 < 4; ++t2) {
            bf16x8 a = *(const bf16x8*)&AstW[t2 * 256 + lane * 4];
            cacc = __builtin_amdgcn_mfma_f32_16x16x32_bf16(a, bfrag[t2], cacc, 0, 0, 0);
        }
#pragma unroll
        for (int reg = 0; reg < 4; ++reg) {
            int row = quad * 4 + reg;
            size_t onode = (size_t)base + row;
            float v2 = cacc[reg] + bias;
            if (RELU) v2 = fmaxf(v2, 0.f);
            if (OUT32) ((float*)outp)[onode * DD + n] = v2;
            else       ((unsigned short*)outp)[onode * DD + n] = f2bf(v2);
        }
    }
}

extern "C" void kernel_launch(void* const* d_in, const int* in_sizes, int n_in,
                              void* d_out, int out_size, void* d_ws, size_t ws_size,
                              hipStream_t stream)
{
    const float* x     = (const float*)d_in[0];
    const int*   ei    = (const int*)d_in[1];
    const float* w     = (const float*)d_in[2];
    const float* Wrel1 = (const float*)d_in[4];
    const float* brel1 = (const float*)d_in[5];
    const float* Wroot1= (const float*)d_in[6];
    const float* Wrel2 = (const float*)d_in[7];
    const float* brel2 = (const float*)d_in[8];
    const float* Wroot2= (const float*)d_in[9];
    const float* Wrel3 = (const float*)d_in[10];
    const float* brel3 = (const float*)d_in[11];
    const float* Wroot3= (const float*)d_in[12];

    float* out = (float*)d_out;

    // workspace layout (all 16B aligned)
    char* ws = (char*)d_ws;
    int2*  ebuf   = (int2*)ws;                 ws += (size_t)NE * 8;            // 10.24 MB
    unsigned short* xb  = (unsigned short*)ws; ws += (size_t)NN * DD * 2;       // 12.8 MB
    unsigned short* hb1 = (unsigned short*)ws; ws += (size_t)NN * DD * 2;       // 12.8 MB
    unsigned short* hb2 = (unsigned short*)ws; ws += (size_t)NN * DD * 2;       // 12.8 MB
    int*   rowptr = (int*)ws;                  ws += (size_t)(NPAD + 16) * 4;
    int*   cur    = (int*)ws;                  ws += (size_t)NPAD * 4;
    int*   deg    = (int*)ws;                  ws += (size_t)NPAD * 4;
    int*   bsum   = (int*)ws;                  ws += (size_t)128 * 4;
    int*   bbase  = (int*)ws;                  ws += (size_t)128 * 4;
    unsigned short* Bp = (unsigned short*)ws;  // 3 * 16 KB

    const int* src = ei;
    const int* dst = ei + NE;

    // ---- CSR build: atomic degree hist -> hierarchical scan -> scatter ----
    hipMemsetAsync(deg, 0, (size_t)NPAD * 4, stream);
    bpack_kernel<<<3, 256, 0, stream>>>(Wrel1, Wroot1, Wrel2, Wroot2, Wrel3, Wroot3, Bp);
    degcnt_kernel<<<1250, 256, 0, stream>>>(dst, deg);
    bsum_kernel<<<NBLK, 256, 0, stream>>>(deg, bsum);
    scan98_kernel<<<1, 128, 0, stream>>>(bsum, bbase, rowptr);
    bscan_kernel<<<NBLK, 256, 0, stream>>>(deg, bbase, rowptr, cur);
    scatter_kernel<<<1250, 256, 0, stream>>>(src, dst, w, cur, ebuf);

    // ---- xb = bf16(x) ----
    f32_to_bf16_kernel<<<6250, 256, 0, stream>>>(x, xb);

    // ---- 3 fused layers (ping-pong xb -> hb1 -> hb2 -> out) ----
    fused_layer_kernel<true, false><<<NN / 16, 512, 0, stream>>>(
        xb, rowptr, ebuf, Bp, brel1, hb1);
    fused_layer_kernel<true, false><<<NN / 16, 512, 0, stream>>>(
        hb1, rowptr, ebuf, Bp + (size_t)4 * 256 * 8, brel2, hb2);
    fused_layer_kernel<false, true><<<NN / 16, 512, 0, stream>>>(
        hb2, rowptr, ebuf, Bp + (size_t)8 * 256 * 8, brel3, out);
}

// Round 4
// 341.482 us; speedup vs baseline: 1.0527x; 1.0527x over previous
//
#include <hip/hip_runtime.h>
#include <hip/hip_bf16.h>

#define NN 100000
#define NE 1280000
#define DD 64
#define RSHIFT 9             // 512-node dst ranges
#define NRANGE 196           // ceil(NN/512)
#define NBLK 98              // scan blocks of 1024 nodes
#define NPAD (NBLK * 1024)   // 100352 (padded node count, deg=0 in pad)

typedef __attribute__((ext_vector_type(8))) short bf16x8;
typedef __attribute__((ext_vector_type(4))) float f32x4;

static __device__ __forceinline__ unsigned short f2bf(float f) {
    __hip_bfloat16 h = __float2bfloat16(f);
    return *reinterpret_cast<unsigned short*>(&h);
}

// ---------------------------------------------------------------------------
// x (fp32) -> bf16 copy. Grid 6250 x 256, 4 elems/thread (exact: 6.4M).
// ---------------------------------------------------------------------------
__global__ __launch_bounds__(256) void f32_to_bf16_kernel(
    const float* __restrict__ in, unsigned short* __restrict__ out)
{
    int i = (blockIdx.x * 256 + threadIdx.x) * 4;
    float4 v = *(const float4*)(in + i);
    ushort4 o;
    o.x = f2bf(v.x); o.y = f2bf(v.y); o.z = f2bf(v.z); o.w = f2bf(v.w);
    *(ushort4*)(out + i) = o;
}

// ---------------------------------------------------------------------------
// B-fragment pre-pack: Bp[layer][t][256 threads][8] bf16. Grid 3.
// ---------------------------------------------------------------------------
__global__ __launch_bounds__(256) void bpack_kernel(
    const float* __restrict__ Wrel1, const float* __restrict__ Wroot1,
    const float* __restrict__ Wrel2, const float* __restrict__ Wroot2,
    const float* __restrict__ Wrel3, const float* __restrict__ Wroot3,
    unsigned short* __restrict__ Bp)
{
    int L = blockIdx.x;
    const float* Wrel  = (L == 0) ? Wrel1  : (L == 1) ? Wrel2  : Wrel3;
    const float* Wroot = (L == 0) ? Wroot1 : (L == 1) ? Wroot2 : Wroot3;
    int tid = threadIdx.x;
    int wv = tid >> 6, lane = tid & 63, quad = lane >> 4, m16 = lane & 15;
    int n = wv * 16 + m16;
    unsigned short* o = Bp + (size_t)L * 4 * 256 * 8;
#pragma unroll
    for (int t = 0; t < 4; ++t)
#pragma unroll
        for (int j = 0; j < 8; ++j) {
            int k = t * 32 + quad * 8 + j;
            float wval = (k < 64) ? Wrel[k * 64 + n] : Wroot[(k - 64) * 64 + n];
            o[((size_t)t * 256 + tid) * 8 + j] = f2bf(wval);
        }
}

// ---------------------------------------------------------------------------
// Degree histogram: non-returning global atomics (fire-and-forget, fast).
// ---------------------------------------------------------------------------
__global__ __launch_bounds__(256) void degcnt_kernel(
    const int* __restrict__ dst, int* __restrict__ deg)
{
    int e0 = (blockIdx.x * 256 + threadIdx.x) * 4;
    int4 d4 = *(const int4*)(dst + e0);
    atomicAdd(&deg[d4.x], 1);
    atomicAdd(&deg[d4.y], 1);
    atomicAdd(&deg[d4.z], 1);
    atomicAdd(&deg[d4.w], 1);
}

// ---------------------------------------------------------------------------
// Hierarchical scan of deg[NPAD] -> rowptr. Step 1: block sums (grid 98).
// ---------------------------------------------------------------------------
__global__ __launch_bounds__(256) void bsum_kernel(
    const int* __restrict__ deg, int* __restrict__ bsum)
{
    __shared__ int sd[256];
    int tid = threadIdx.x;
    int4 c = *(const int4*)(deg + blockIdx.x * 1024 + tid * 4);
    sd[tid] = c.x + c.y + c.z + c.w;
    __syncthreads();
    for (int o = 128; o > 0; o >>= 1) {
        if (tid < o) sd[tid] += sd[tid + o];
        __syncthreads();
    }
    if (tid == 0) bsum[blockIdx.x] = sd[0];
}

// Step 2: exclusive scan of 98 block sums (1 block).
__global__ __launch_bounds__(128) void scan98_kernel(
    const int* __restrict__ bsum, int* __restrict__ bbase,
    int* __restrict__ rowptr)
{
    __shared__ int sd[128];
    int tid = threadIdx.x;
    int v = (tid < NBLK) ? bsum[tid] : 0;
    sd[tid] = v;
    __syncthreads();
    for (int o = 1; o < 128; o <<= 1) {
        int t = (tid >= o) ? sd[tid - o] : 0;
        __syncthreads();
        sd[tid] += t;
        __syncthreads();
    }
    if (tid < NBLK) bbase[tid] = sd[tid] - v;
    if (tid == 0) rowptr[NPAD] = NE;
}

// Step 3: per-block scan of 1024 degs -> rowptr + range cursors gcur (grid 98).
// Each block covers exactly 2 ranges of 512 nodes -> emits gcur[2b], gcur[2b+1].
__global__ __launch_bounds__(256) void bscan_kernel(
    const int* __restrict__ deg, const int* __restrict__ bbase,
    int* __restrict__ rowptr, int* __restrict__ gcur)
{
    __shared__ int ssum[256];
    int tid = threadIdx.x;
    int n0 = blockIdx.x * 1024 + tid * 4;
    int4 c = *(const int4*)(deg + n0);
    int s = c.x + c.y + c.z + c.w;
    ssum[tid] = s;
    __syncthreads();
    for (int o = 1; o < 256; o <<= 1) {
        int t = (tid >= o) ? ssum[tid - o] : 0;
        __syncthreads();
        ssum[tid] += t;
        __syncthreads();
    }
    int base = bbase[blockIdx.x] + ssum[tid] - s;
    int4 r;
    r.x = base; r.y = base + c.x; r.z = r.y + c.y; r.w = r.z + c.z;
    *(int4*)(rowptr + n0) = r;
    if (tid == 0)   gcur[2 * blockIdx.x]     = base;   // rowptr[b*1024]
    if (tid == 128) gcur[2 * blockIdx.x + 1] = base;   // rowptr[b*1024+512]
}

// ---------------------------------------------------------------------------
// P1: coarse bin by dst range. 512 thr, 2 edges/thr, wave-shfl scans ->
// only 5 barriers/block (vs ~35 in the Hillis-Steele version).
// Record packs: src (17b) | local-dst (9b @ bit17).
// ---------------------------------------------------------------------------
__global__ __launch_bounds__(512) void p1_bin_kernel(
    const int* __restrict__ src, const int* __restrict__ dst,
    const float* __restrict__ w, int* __restrict__ gcur,
    int2* __restrict__ ecoarse)
{
    __shared__ int2 stage[1024];
    __shared__ unsigned char sbkt[1024];
    __shared__ int cnt[256], ofs[256], gpos[256];
    __shared__ int wsum[4];

    int tid = threadIdx.x;
    int e0 = blockIdx.x * 1024 + tid * 2;
    int2   s2 = *(const int2*)(src + e0);
    int2   d2 = *(const int2*)(dst + e0);
    float2 w2 = *(const float2*)(w + e0);

    if (tid < 256) cnt[tid] = 0;
    __syncthreads();

    int ss[2] = {s2.x, s2.y};
    int dd[2] = {d2.x, d2.y};
    float ww[2] = {w2.x, w2.y};
    int b[2], p[2];
#pragma unroll
    for (int i = 0; i < 2; ++i) {
        b[i] = dd[i] >> RSHIFT;
        p[i] = atomicAdd(&cnt[b[i]], 1);
    }
    __syncthreads();

    // wave-level inclusive scan of 256 bins (4 waves x 64 lanes)
    if (tid < 256) {
        int v = cnt[tid];
        int lane6 = tid & 63;
        int sum = v;
#pragma unroll
        for (int o = 1; o < 64; o <<= 1) {
            int t = __shfl_up(sum, o);
            if (lane6 >= o) sum += t;
        }
        if (lane6 == 63) wsum[tid >> 6] = sum;
        ofs[tid] = sum - v;               // wave-local exclusive
    }
    __syncthreads();
    if (tid < 256) {
        int wid = tid >> 6;
        int pre = 0;
#pragma unroll
        for (int k = 0; k < 3; ++k) pre += (k < wid) ? wsum[k] : 0;
        ofs[tid] += pre;
        int cv = cnt[tid];
        if (tid < NRANGE && cv > 0) gpos[tid] = atomicAdd(&gcur[tid], cv);
    }
    __syncthreads();

#pragma unroll
    for (int i = 0; i < 2; ++i) {
        int slot = ofs[b[i]] + p[i];
        stage[slot] = make_int2(ss[i] | ((dd[i] & 511) << 17), __float_as_int(ww[i]));
        sbkt[slot] = (unsigned char)b[i];
    }
    __syncthreads();

#pragma unroll
    for (int u = 0; u < 2; ++u) {
        int j = tid + u * 512;
        int bb = sbkt[j];
        ecoarse[gpos[bb] + (j - ofs[bb])] = stage[j];
    }
}

// ---------------------------------------------------------------------------
// P2: place within range using LDS cursors preloaded from rowptr (no counting
// pass, no scan). Grid NRANGE x 1024 thr, single sweep, LDS returning atomics.
// ---------------------------------------------------------------------------
__global__ __launch_bounds__(1024) void p2_place_kernel(
    const int2* __restrict__ ecoarse, const int* __restrict__ rowptr,
    int2* __restrict__ ebuf)
{
    __shared__ int cur[512];
    int r = blockIdx.x, tid = threadIdx.x;
    int n0 = r << RSHIFT;
    if (tid < 512) cur[tid] = rowptr[n0 + tid];
    int beg = rowptr[n0];
    int end = rowptr[n0 + 512];
    __syncthreads();

    for (int j = beg + tid; j < end; j += 1024) {
        int2 rec = ecoarse[j];
        int dl = (rec.x >> 17) & 511;
        int pp = atomicAdd(&cur[dl], 1);
        ebuf[pp] = make_int2(rec.x & 0x1FFFF, rec.y);
    }
}

// ---------------------------------------------------------------------------
// FUSED layer: CSR gather + dual GEMM + bias (+ReLU). Block = 512 thr =
// 8 waves = 16 nodes. Half-wave per node: 32 lanes = 32 channel pairs,
// unroll-16 slots -> 32 gathers in flight per wave (2x round 2). Edges
// staged with one cooperative ebuf load, distributed by __shfl. Agg + root
// rows packed into LDS in MFMA fragment order, one barrier, waves 0-3 run
// 4 chained MFMAs + epilogue. Ping-pong in/out tables.
// ---------------------------------------------------------------------------
template <bool RELU, bool OUT32>
__global__ __launch_bounds__(512) void fused_layer_kernel(
    const unsigned short* __restrict__ hb,   // input node table (gather + root)
    const int* __restrict__ rowptr,
    const int2* __restrict__ ebuf,
    const unsigned short* __restrict__ Bp,   // [4][256][8] bf16 (this layer)
    const float* __restrict__ brel,
    void* __restrict__ outp)
{
    __shared__ __align__(16) unsigned int AstW[4 * 256];   // 4 KB

    int tid = threadIdx.x;
    int lane = tid & 63;
    int wv = tid >> 6;            // 0..7
    int half = lane >> 5;         // node parity within wave
    int ch = lane & 31;           // channel pair
    int base = blockIdx.x * 16;
    int node = base + wv * 2 + half;

    const unsigned int* __restrict__ hw = (const unsigned int*)hb;

    // B fragments + bias preloaded (only used by waves 0-3) so their L2
    // latency hides under the gather.
    bf16x8 bfrag[4];
    float bias = 0.f;
    if (wv < 4) {
#pragma unroll
        for (int t2 = 0; t2 < 4; ++t2)
            bfrag[t2] = *(const bf16x8*)(Bp + ((size_t)t2 * 256 + tid) * 8);
        bias = brel[(wv << 4) | (lane & 15)];
    }

    // root row (own node) issued early
    unsigned rootp = hw[(size_t)node * 32 + ch];

    int beg = rowptr[node];
    int end = rowptr[node + 1];
    int deg = end - beg;

    float aL[4] = {0.f, 0.f, 0.f, 0.f};
    float aH[4] = {0.f, 0.f, 0.f, 0.f};
    for (int c = 0; c < deg; c += 32) {
        int rem = deg - c;
        int nsl = rem < 32 ? rem : 32;
        int idx = (ch < nsl) ? (c + ch) : c;
        int2 e = ebuf[beg + idx];
        float wt = (ch < nsl) ? __int_as_float(e.y) : 0.f;

        for (int s0 = 0; s0 < nsl; s0 += 16) {
#pragma unroll
            for (int i = 0; i < 16; ++i) {
                int slot = s0 + i;
                bool ok = slot < nsl;
                int sl = (half << 5) | (ok ? slot : 0);
                int sr = __shfl(e.x, sl);
                float w = __shfl(wt, sl);
                w = ok ? w : 0.f;
                unsigned v = hw[(size_t)sr * 32 + ch];
                aL[i & 3] = fmaf(w, __uint_as_float(v << 16), aL[i & 3]);
                aH[i & 3] = fmaf(w, __uint_as_float(v & 0xFFFF0000u), aH[i & 3]);
            }
        }
    }
    float accL = (aL[0] + aL[1]) + (aL[2] + aL[3]);
    float accH = (aH[0] + aH[1]) + (aH[2] + aH[3]);

    // stage agg (k 0..63) and root (k 64..127) pairs in fragment order
    int m = wv * 2 + half;                     // row 0..15
    int t = ch >> 4, q = (ch >> 2) & 3, jj = ch & 3;
    unsigned pack = ((unsigned)f2bf(accH) << 16) | (unsigned)f2bf(accL);
    AstW[t * 256 + (q * 16 + m) * 4 + jj] = pack;
    AstW[(2 + t) * 256 + (q * 16 + m) * 4 + jj] = rootp;
    __syncthreads();

    if (wv < 4) {
        int quad = lane >> 4, m16 = lane & 15;
        int n = wv * 16 + m16;
        f32x4 cacc = {0.f, 0.f, 0.f, 0.f};
#pragma unroll
        for (int t2 = 0; t2 < 4; ++t2) {
            bf16x8 a = *(const bf16x8*)&AstW[t2 * 256 + lane * 4];
            cacc = __builtin_amdgcn_mfma_f32_16x16x32_bf16(a, bfrag[t2], cacc, 0, 0, 0);
        }
#pragma unroll
        for (int reg = 0; reg < 4; ++reg) {
            int row = quad * 4 + reg;
            size_t onode = (size_t)base + row;
            float v2 = cacc[reg] + bias;
            if (RELU) v2 = fmaxf(v2, 0.f);
            if (OUT32) ((float*)outp)[onode * DD + n] = v2;
            else       ((unsigned short*)outp)[onode * DD + n] = f2bf(v2);
        }
    }
}

extern "C" void kernel_launch(void* const* d_in, const int* in_sizes, int n_in,
                              void* d_out, int out_size, void* d_ws, size_t ws_size,
                              hipStream_t stream)
{
    const float* x     = (const float*)d_in[0];
    const int*   ei    = (const int*)d_in[1];
    const float* w     = (const float*)d_in[2];
    const float* Wrel1 = (const float*)d_in[4];
    const float* brel1 = (const float*)d_in[5];
    const float* Wroot1= (const float*)d_in[6];
    const float* Wrel2 = (const float*)d_in[7];
    const float* brel2 = (const float*)d_in[8];
    const float* Wroot2= (const float*)d_in[9];
    const float* Wrel3 = (const float*)d_in[10];
    const float* brel3 = (const float*)d_in[11];
    const float* Wroot3= (const float*)d_in[12];

    float* out = (float*)d_out;

    // workspace layout (all 16B aligned)
    char* ws = (char*)d_ws;
    int2*  ebuf    = (int2*)ws;                ws += (size_t)NE * 8;            // 10.24 MB
    int2*  ecoarse = (int2*)ws;                                                // aliases xb
    unsigned short* xb  = (unsigned short*)ws; ws += (size_t)NN * DD * 2;       // 12.8 MB (>= ecoarse 10.24)
    unsigned short* hb1 = (unsigned short*)ws; ws += (size_t)NN * DD * 2;       // 12.8 MB
    unsigned short* hb2 = (unsigned short*)ws; ws += (size_t)NN * DD * 2;       // 12.8 MB
    int*   rowptr = (int*)ws;                  ws += (size_t)(NPAD + 16) * 4;
    int*   deg    = (int*)ws;                  ws += (size_t)NPAD * 4;
    int*   bsum   = (int*)ws;                  ws += (size_t)128 * 4;
    int*   bbase  = (int*)ws;                  ws += (size_t)128 * 4;
    int*   gcur   = (int*)ws;                  ws += (size_t)256 * 4;
    unsigned short* Bp = (unsigned short*)ws;  // 3 * 16 KB

    const int* src = ei;
    const int* dst = ei + NE;

    // ---- CSR build: degree hist -> hierarchical scan -> 2-phase bin/place ----
    hipMemsetAsync(deg, 0, (size_t)NPAD * 4, stream);
    bpack_kernel<<<3, 256, 0, stream>>>(Wrel1, Wroot1, Wrel2, Wroot2, Wrel3, Wroot3, Bp);
    degcnt_kernel<<<1250, 256, 0, stream>>>(dst, deg);
    bsum_kernel<<<NBLK, 256, 0, stream>>>(deg, bsum);
    scan98_kernel<<<1, 128, 0, stream>>>(bsum, bbase, rowptr);
    bscan_kernel<<<NBLK, 256, 0, stream>>>(deg, bbase, rowptr, gcur);
    p1_bin_kernel<<<1250, 512, 0, stream>>>(src, dst, w, gcur, ecoarse);
    p2_place_kernel<<<NRANGE, 1024, 0, stream>>>(ecoarse, rowptr, ebuf);

    // ---- xb = bf16(x) (ecoarse dead now) ----
    f32_to_bf16_kernel<<<6250, 256, 0, stream>>>(x, xb);

    // ---- 3 fused layers (ping-pong xb -> hb1 -> hb2 -> out) ----
    fused_layer_kernel<true, false><<<NN / 16, 512, 0, stream>>>(
        xb, rowptr, ebuf, Bp, brel1, hb1);
    fused_layer_kernel<true, false><<<NN / 16, 512, 0, stream>>>(
        hb1, rowptr, ebuf, Bp + (size_t)4 * 256 * 8, brel2, hb2);
    fused_layer_kernel<false, true><<<NN / 16, 512, 0, stream>>>(
        hb2, rowptr, ebuf, Bp + (size_t)8 * 256 * 8, brel3, out);
}